// Round 7
// baseline (222.799 us; speedup 1.0000x reference)
//
#include <hip/hip_runtime.h>

typedef int v4i  __attribute__((ext_vector_type(4)));
typedef int v16i __attribute__((ext_vector_type(16)));

#define QMAX 127.0f

// ---- workspace layout ----
// xq  : int8 padded, swizzled [16][66][66 px][5 c5][4 slots][16]
//       slot s of (col,c5) holds logical ci-chunk s ^ ((col>>1)&3)
// wq2 : int8 fragment-order for 32x32x32 MFMA: [9 p][5 c5][2 ks][10 cot][64 lane][16]
//       lane holds co = cot*32 + (lane&31), ci = c5*64 + ks*32 + (lane>>5)*16 + j
// bi  : float [320]
#define XQ_BYTES 22302720
#define WQ_BYTES 921600

__device__ __forceinline__ float clampf(float v, float lo, float hi) {
    return fminf(fmaxf(v, lo), hi);
}

// Bit-exact fast round(v/step): reciprocal multiply, exact-division fallback
// only near half-integer boundaries (trigger ~7e-4; 50x error margin).
__device__ __forceinline__ float qround(float v, float step, float inv) {
    float t = v * inv;
    float r = rintf(t);
    float d = fabsf(t - r);
    if (fabsf(d - 0.5f) < fabsf(t) * 1e-5f + 1e-5f)
        r = rintf(v / step);
    return r;
}

__device__ __forceinline__ void gload_lds16(const char* g, char* l) {
    __builtin_amdgcn_global_load_lds(
        (const __attribute__((address_space(1))) void*)g,
        (__attribute__((address_space(3))) void*)l, 16, 0, 0);
}

__device__ __forceinline__ v16i mfma32_i8(v4i a, v4i b, v16i c) {
    return __builtin_amdgcn_mfma_i32_32x32x32_i8(a, b, c, 0, 0, 0);
}

// ---------------------------------------------------------------------------
// Fused producer kernel:
//   blocks [0,1024)    : x quantize (block = (h,b)), long pole -> first
//   blocks [1024,1124) : wq2 quantize into 32x32x32 fragment order
//   blocks [1124,1449) : xq halo zeroing
//   block  1449        : bias requant
// ---------------------------------------------------------------------------
__global__ __launch_bounds__(256) void fused_prep_kernel(
    const float* __restrict__ x, const float* __restrict__ w,
    const float* __restrict__ bias,
    const float* __restrict__ step_x_p, const float* __restrict__ step_w_p,
    const float* __restrict__ step_b_p, const float* __restrict__ shift_p,
    char* __restrict__ xq, char* __restrict__ wq2, float* __restrict__ bi)
{
    // x-quant uses F as [64][65]; wq uses F as [32][289] (36,992 B)
    __shared__ float F[32 * 289];
    const int bid = blockIdx.x;
    const int t = threadIdx.x;

    if (bid < 1024) {
        // ---- x quantize: one block per (h,b); writes row h+1 interior ----
        const int h = bid & 63;
        const int b = bid >> 6;
        const float step = *step_x_p;
        const float inv  = 1.0f / step;
        const int wcol = t >> 2;       // output col-1 (0..63)
        const int cg   = t & 3;        // logical 16-ci chunk within c5
        v4i vals[5];

        for (int c5 = 0; c5 < 5; ++c5) {
            {
                const int r = t >> 4, c = (t & 15) * 4;
                const float* src = x + (((size_t)(b * 320 + c5 * 64) * 64 + h) * 64);
#pragma unroll
                for (int i = 0; i < 4; ++i) {
                    const int row = r + i * 16;
                    *(float4*)&F[row * 65 + c] =
                        *(const float4*)(src + (size_t)row * 4096 + c);
                }
            }
            __syncthreads();
            int dws[4];
#pragma unroll
            for (int j = 0; j < 4; ++j) {
                int word = 0;
#pragma unroll
                for (int k = 0; k < 4; ++k) {
                    float v = F[(cg * 16 + j * 4 + k) * 65 + wcol];
                    int xi = (int)clampf(qround(v, step, inv), -QMAX, QMAX);
                    word |= (xi & 0xFF) << (8 * k);
                }
                dws[j] = word;
            }
            vals[c5] = (v4i){dws[0], dws[1], dws[2], dws[3]};
            __syncthreads();
        }

        const int col = wcol + 1;
        const int key = (col >> 1) & 3;
        char* base = xq + ((size_t)(b * 66 + (h + 1)) * 66 + col) * 320;
#pragma unroll
        for (int c5 = 0; c5 < 5; ++c5)
            *(v4i*)(base + c5 * 64 + (((cg ^ key)) << 4)) = vals[c5];

    } else if (bid < 1124) {
        // ---- weight quantize into 32x32x32 fragment order ----
        // block = (cot, c5, ks): stage 32 co x 32 ci x 9 p floats, then emit
        // one coalesced 1024B block per p.
        const int blk = bid - 1024;      // 0..99
        const int cot = blk / 10;        // 0..9  (32-co tile)
        const int rem = blk - cot * 10;
        const int c5  = rem >> 1;        // 0..4
        const int ks  = rem & 1;         // 0..1  (32-ci half of c5)
        const float step = *step_w_p;
        const float inv  = 1.0f / step;

        for (int idx = t; idx < 2304; idx += 256) {
            const int co_l = idx / 72;
            const int m4   = idx - co_l * 72;
            const float4 v = *(const float4*)(
                w + (size_t)(cot * 32 + co_l) * 2880 + c5 * 576 + ks * 288 + m4 * 4);
            float* dst = &F[co_l * 289 + m4 * 4];
            dst[0] = v.x; dst[1] = v.y; dst[2] = v.z; dst[3] = v.w;
        }
        __syncthreads();

        // thread t writes bytes [t*4, t*4+4) of each p's 1024B block:
        // lane = t>>2, j0 = (t&3)*4; co_l = lane&31; ci_l = (lane>>5)*16+j0+k
        const int co_l = (t >> 2) & 31;
        const int cib  = (t >> 7) * 16 + (t & 3) * 4;
        char* dst = wq2 + (size_t)(c5 * 20 + ks * 10 + cot) * 1024 + t * 4;
#pragma unroll
        for (int p = 0; p < 9; ++p) {
            int word = 0;
#pragma unroll
            for (int k = 0; k < 4; ++k) {
                float v = F[co_l * 289 + (cib + k) * 9 + p];
                int q = (int)clampf(qround(v, step, inv), -QMAX, QMAX);
                word |= (q & 0xFF) << (8 * k);
            }
            *(int*)(dst + (size_t)p * 102400) = word;
        }
    } else if (bid < 1449) {
        // ---- halo zeroing ----
        int tid = (bid - 1124) * 256 + t;
        if (tid < 83200) {
            int b = tid / 5200;
            int r = tid - b * 5200;
            int px = r / 20;
            int ck = (r - px * 20) * 16;
            int row, col;
            if (px < 66)       { row = 0;  col = px; }
            else if (px < 132) { row = 65; col = px - 66; }
            else { int e = px - 132; row = 1 + (e >> 1); col = (e & 1) * 65; }
            size_t off = ((size_t)(b * 66 + row) * 66 + col) * 320 + ck;
            v4i z = {0, 0, 0, 0};
            *(v4i*)&xq[off] = z;
        }
    } else {
        // ---- bias requant ----
        const float step_b = *step_b_p;
        const float xs = 1.0f / *step_x_p;
        const float ws = 1.0f / *step_w_p;
        const float shift = *shift_p;
#pragma unroll
        for (int co = t; co < 320; co += 256) {
            float b_deq = clampf(rintf(bias[co] / step_b), -QMAX, QMAX) * step_b;
            float v = ((b_deq * shift) * xs) * ws;
            bi[co] = clampf(rintf(v), -QMAX, QMAX);
        }
    }
}

// ---------------------------------------------------------------------------
// Implicit-GEMM conv — v_mfma_i32_32x32x32_i8 (round-7).
// Round-4 structure preserved exactly (grid 1280, XCD remap, dbuf B staging,
// A distance-1 dbuf, 3 waves/SIMD) — only the MFMA core changes:
// 8 x 32x32x32 per p (was 16 x 16x16x64): half the instructions, each 2x the
// ops, ceiling 4404 vs 3944 TOPS (+12%), half the load->MFMA handoffs.
// B-fragment (col=lane&31, k=(lane>>5)*16+j) reads the EXISTING xq LDS
// layout with chunk = 2*ks + (lane>>5); per-16-lane bank trace: starts
// {0,4,8,12,16,20,24,28}x2 -> conflict-free (unchanged).
// ROUND-3 LESSON: no ptile pairing (TLP across blocks is the lever).
// ROUND-5 LESSON: no small-tile retile (A L2 traffic + phase cover).
// ROUND-6 LESSON: no distance-2 prefetch (compiler schedule already good).
// ---------------------------------------------------------------------------
__global__ __launch_bounds__(256, 3) void conv_mfma_kernel(
    const char* __restrict__ xq, const char* __restrict__ wq2,
    const float* __restrict__ bi, const float* __restrict__ shift_p,
    float* __restrict__ out)
{
    __shared__ __attribute__((aligned(16))) char B_lds[2][25344]; // 6 rows x 66 x 64

    const int t  = threadIdx.x;
    const int id = blockIdx.x;           // 0..1279
    // id = (ptile&7) + 8*bx + 40*(ptile>>3)  -- invert:
    const int g  = id / 40;
    const int r  = id - g * 40;
    const int bx = r >> 3;               // co tile 0..4 (64 co each)
    const int ptile = (g << 3) | (r & 7);

    const int co0 = bx * 64;
    const int b  = ptile >> 4;
    const int h0 = (ptile & 15) * 4;

    const int wave = t >> 6, lane = t & 63;
    const int l31 = lane & 31, hi = lane >> 5;

    const char* xbase = xq + ((size_t)(b * 66 + h0) * 66) * 320;

    v16i acc[2][2] = {};   // [ct (32-co tile)][h (32-px half)]

    // prologue: stage c5=0 into buffer 0
    for (int c = t; c < 1584; c += 256) {
        const char* gp = xbase + (c >> 2) * 320 + ((c & 3) << 4);
        gload_lds16(gp, &B_lds[0][(c - lane) * 16]);
    }
    __syncthreads();

    for (int c5 = 0; c5 < 5; ++c5) {
        // issue next stage's DMA first (other buffer; drained by the barrier
        // AFTER this c5's compute -> fully overlapped)
        if (c5 < 4) {
            const int ci0 = (c5 + 1) * 64;
            char* dst = B_lds[(c5 + 1) & 1];
            for (int c = t; c < 1584; c += 256) {
                const char* gp = xbase + (c >> 2) * 320 + ci0 + ((c & 3) << 4);
                gload_lds16(gp, &dst[(c - lane) * 16]);
            }
        }

        const char* Bc = B_lds[c5 & 1];
        const char* wp = wq2 + (c5 * 20 + bx * 2) * 1024 + lane * 16;

        // A distance-1 double-buffer: [buf][ct][ks]
        v4i areg[2][2][2];
#pragma unroll
        for (int ct = 0; ct < 2; ++ct)
#pragma unroll
            for (int ks = 0; ks < 2; ++ks)
                areg[0][ct][ks] = *(const v4i*)(wp + ks * 10240 + ct * 1024);

#pragma unroll
        for (int p = 0; p < 9; ++p) {
            const int dh = p / 3, dw = p - dh * 3;
            if (p < 8) {
#pragma unroll
                for (int ct = 0; ct < 2; ++ct)
#pragma unroll
                    for (int ks = 0; ks < 2; ++ks)
                        areg[(p + 1) & 1][ct][ks] = *(const v4i*)(
                            wp + (p + 1) * 102400 + ks * 10240 + ct * 1024);
            }
            const int prow = wave + dh;
            v4i bf[2][2];  // [h][ks]
#pragma unroll
            for (int h = 0; h < 2; ++h) {
                const int col = h * 32 + l31 + dw;
                const int key = (col >> 1) & 3;
                const int base = (prow * 66 + col) * 64;
#pragma unroll
                for (int ks = 0; ks < 2; ++ks)
                    bf[h][ks] = *(const v4i*)&Bc[base +
                                                 (((2 * ks + hi) ^ key) << 4)];
            }
            __builtin_amdgcn_s_setprio(1);
#pragma unroll
            for (int ks = 0; ks < 2; ++ks)      // ks outer: acc-reuse dist 4
#pragma unroll
                for (int h = 0; h < 2; ++h)
#pragma unroll
                    for (int ct = 0; ct < 2; ++ct)
                        acc[ct][h] = mfma32_i8(areg[p & 1][ct][ks], bf[h][ks],
                                               acc[ct][h]);
            __builtin_amdgcn_s_setprio(0);
        }
        __syncthreads();
    }

    // epilogue: y_shift = clip(rint(y*shift)); out = clip(y_shift + b_int8)
    // C/D 32x32: col = lane&31 (px), row = (reg&3) + 8*(reg>>2) + 4*hi (co)
    const float shift = *shift_p;
    const int h = h0 + wave;
#pragma unroll
    for (int ct = 0; ct < 2; ++ct) {
#pragma unroll
        for (int reg = 0; reg < 16; ++reg) {
            const int row = (reg & 3) + 8 * (reg >> 2) + 4 * hi;
            const int co = co0 + ct * 32 + row;
            const float bv = bi[co];
            float* orow = out + (((size_t)(b * 320 + co) * 64) + h) * 64;
#pragma unroll
            for (int hh = 0; hh < 2; ++hh) {
                float y  = (float)acc[ct][hh][reg];
                float ys = clampf(rintf(y * shift), -QMAX, QMAX);
                orow[hh * 32 + l31] = clampf(ys + bv, -QMAX, QMAX);
            }
        }
    }
}

extern "C" void kernel_launch(void* const* d_in, const int* in_sizes, int n_in,
                              void* d_out, int out_size, void* d_ws, size_t ws_size,
                              hipStream_t stream) {
    const float* x      = (const float*)d_in[0];
    const float* w      = (const float*)d_in[1];
    const float* bias   = (const float*)d_in[2];
    const float* step_x = (const float*)d_in[3];
    const float* step_w = (const float*)d_in[4];
    const float* step_b = (const float*)d_in[5];
    const float* shift  = (const float*)d_in[6];
    float* out = (float*)d_out;

    char*  xq  = (char*)d_ws;
    char*  wq2 = xq + XQ_BYTES;
    float* bi  = (float*)(wq2 + WQ_BYTES);

    fused_prep_kernel<<<1450, 256, 0, stream>>>(x, w, bias, step_x, step_w,
                                                step_b, shift, xq, wq2, bi);
    conv_mfma_kernel<<<1280, 256, 0, stream>>>(xq, wq2, bi, shift, out);
}